// Round 13
// baseline (419.321 us; speedup 1.0000x reference)
//
#include <hip/hip_runtime.h>
#include <hip/hip_bf16.h>

#define NN   50000
#define NE   800000
#define MP   3
#define DIN  128
#define DF   256     // HEADS*OUT_DIM
#define NH   8
#define HID  128
#define NC   (MP*NN)              // 150000

#define NBIN   196                // bin = dst >> 8
#define BINCAP 5120               // >=16 sigma above Poisson mean 4082
#define G1_EPB 4096               // edges per k_part block
#define G1_EPT (G1_EPB / 256)     // 16
#define G1_NB  ((NE + G1_EPB - 1) / G1_EPB)   // 196
#define G2_EPT (BINCAP / 256)     // 20

typedef unsigned short u16;
typedef unsigned int   u32;
typedef __attribute__((ext_vector_type(8))) short bf16x8;   // MFMA A/B frag
typedef __attribute__((ext_vector_type(4))) float f32x4;    // MFMA C/D frag
typedef __attribute__((ext_vector_type(2))) float f32x2;    // pk-math pair

__device__ __forceinline__ float bf2f(u16 u) {
    return __uint_as_float(((u32)u) << 16);
}
__device__ __forceinline__ u16 f2bf(float f) {
    u32 x = __float_as_uint(f);
    u32 r = x + 0x7fffu + ((x >> 16) & 1u);   // round-to-nearest-even
    return (u16)(r >> 16);
}
__device__ __forceinline__ f32x2 bfp(u32 u) {   // unpack bf16 pair -> f32x2
    f32x2 r;
    r.x = __uint_as_float(u << 16);
    r.y = __uint_as_float(u & 0xffff0000u);
    return r;
}
__device__ __forceinline__ float tanh_fast(float x) {
    float c = fminf(fmaxf(x, -15.f), 15.f);
    float t = __expf(2.f * c);
    return (t - 1.f) / (t + 1.f);
}

// ---------------------------------------------------------------------------
// 0) FUSED k_part + k_cvt (R12, proven). Partition blocks [0, MP*G1_NB):
//    LDS-atomic ranks, one device atomic per (block,bin). Conversion blocks
//    behind: h->hb, Wg->WgT, W1->W1T, WAL->WALT.
// ---------------------------------------------------------------------------
#define CVT_H_N   (NN * DIN / 8)          // 800000
#define CVT_WG_N  (MP * DF * DIN)         // 98304
#define CVT_W1_N  (HID * DF)              // 32768
#define CVT_WAL_N (MP * 16 * DIN)         // 6144
#define CVT_TOT_N (CVT_H_N + CVT_WG_N + CVT_W1_N + CVT_WAL_N)   // 937216
#define CVT_NB    ((CVT_TOT_N + 255) / 256)                     // 3661
#define PART_NB   (MP * G1_NB)                                  // 588
#define PC_NB     (PART_NB + CVT_NB)                            // 4249
__global__ __launch_bounds__(256) void k_part_cvt(
    const int* __restrict__ src, const int* __restrict__ dst,
    int* __restrict__ binCnt, u32* __restrict__ part,
    const float* __restrict__ h, const float* __restrict__ Wg, const float* __restrict__ W1,
    const float* __restrict__ al, const float* __restrict__ ar,
    u16* __restrict__ hb, u16* __restrict__ WgT, u16* __restrict__ W1T, u16* __restrict__ WALT)
{
    __shared__ int hist[NBIN];
    __shared__ int base[NBIN];
    const int t = threadIdx.x;
    if (blockIdx.x < PART_NB) {   // ---- partition path ----
        const int m  = blockIdx.x / G1_NB;
        const int bx = blockIdx.x - m * G1_NB;
        if (t < NBIN) hist[t] = 0;
        __syncthreads();

        const int e0 = bx * G1_EPB;
        u32 pk[G1_EPT];
        int bn[G1_EPT];
        int rk[G1_EPT];
#pragma unroll
        for (int i = 0; i < G1_EPT; i++) {
            int e = e0 + i * 256 + t;
            bn[i] = -1;
            if (e < NE) {
                int d = dst[(size_t)m * NE + e];
                int s = src[(size_t)m * NE + e];
                bn[i] = d >> 8;
                pk[i] = (u32)s | ((u32)(d & 255) << 16);
                rk[i] = atomicAdd(&hist[bn[i]], 1);
            }
        }
        __syncthreads();
        if (t < NBIN)
            base[t] = hist[t] > 0 ? atomicAdd(&binCnt[m * NBIN + t], hist[t]) : 0;
        __syncthreads();
#pragma unroll
        for (int i = 0; i < G1_EPT; i++) {
            if (bn[i] >= 0) {
                int pos = base[bn[i]] + rk[i];
                if (pos < BINCAP)
                    part[((size_t)(m * NBIN + bn[i])) * BINCAP + pos] = pk[i];
            }
        }
        return;
    }
    // ---- conversion path ----
    int gid = (blockIdx.x - PART_NB) * 256 + t;
    if (gid < CVT_H_N) {
        size_t i8 = (size_t)gid * 8;
        float4 a = *(const float4*)(h + i8);
        float4 b = *(const float4*)(h + i8 + 4);
        uint4 o;
        o.x = (u32)f2bf(a.x) | ((u32)f2bf(a.y) << 16);
        o.y = (u32)f2bf(a.z) | ((u32)f2bf(a.w) << 16);
        o.z = (u32)f2bf(b.x) | ((u32)f2bf(b.y) << 16);
        o.w = (u32)f2bf(b.z) | ((u32)f2bf(b.w) << 16);
        *(uint4*)(hb + i8) = o;
    } else if (gid < CVT_H_N + CVT_WG_N) {
        int g = gid - CVT_H_N;
        int k = g % DIN, n = (g / DIN) % DF, m = g / (DIN * DF);
        WgT[g] = f2bf(Wg[((size_t)m * DIN + k) * DF + n]);
    } else if (gid < CVT_H_N + CVT_WG_N + CVT_W1_N) {
        int g = gid - CVT_H_N - CVT_WG_N;
        int k = g % DF, n = g / DF;
        W1T[g] = f2bf(W1[(size_t)k * HID + n]);
    } else if (gid < CVT_TOT_N) {
        int g = gid - CVT_H_N - CVT_WG_N - CVT_W1_N;
        int k = g & (DIN - 1), c = (g >> 7) & 15, m = g >> 11;
        int hh = c & 7;
        const float* a  = (c < 8 ? al : ar) + ((size_t)m * NH + hh) * 32;
        const float* wg = Wg + ((size_t)m * DIN + k) * DF + 32 * hh;
        float s = 0.f;
#pragma unroll
        for (int d = 0; d < 32; d++) s += wg[d] * a[d];
        WALT[g] = f2bf(s);
    }
}

// ---------------------------------------------------------------------------
// 1) FUSED k_group + k_gemm_feat. Both depend only on k_part_cvt; no mutual
//    dependence. Group blocks [0, PART_NB=588) build the CSR (LDS aliased
//    into the gemm staging buffer); gemm blocks behind do feat = h @ Wg with
//    LDS-staged B-panel (XOR swizzle chunk ^= row&7). Group's ~10us hides
//    under gemm's 2346 blocks.
// ---------------------------------------------------------------------------
#define BS_B_U16  (DF * DIN)               // 32768 u16 = 64KB
#define GEMM_NBX  ((NN + 63) / 64)         // 782
#define GG_NB     (PART_NB + GEMM_NBX * MP)  // 588 + 2346
__global__ __launch_bounds__(256) void k_group_gemm(
    const int* __restrict__ binCnt, const u32* __restrict__ part,
    u16* __restrict__ srcg, int* __restrict__ rowst, int* __restrict__ deg,
    const u16* __restrict__ hb, const u16* __restrict__ WgT, const u16* __restrict__ WALT,
    u16* __restrict__ feat, float* __restrict__ el, float* __restrict__ er)
{
    __shared__ __align__(16) u16 Bs[BS_B_U16 + 16 * DIN];   // 68KB -> 2 blocks/CU
    const int tid = threadIdx.x;

    if (blockIdx.x < PART_NB) {   // ---- group path (CSR build) ----
        int* hist = (int*)Bs;            // 1KB alias
        int* pre  = (int*)Bs + 256;      // 1KB alias
        const int m   = blockIdx.x / NBIN;
        const int bin = blockIdx.x - m * NBIN;
        const int t = tid;
        hist[t] = 0;
        __syncthreads();

        int cnt = binCnt[m * NBIN + bin];
        cnt = cnt < BINCAP ? cnt : BINCAP;
        const u32* pp = part + ((size_t)(m * NBIN + bin)) * BINCAP;

        u32 pk[G2_EPT];
        int rk[G2_EPT];
#pragma unroll
        for (int i = 0; i < G2_EPT; i++) {
            int j = i * 256 + t;
            rk[i] = -1;
            if (j < cnt) {
                u32 p = pp[j];
                pk[i] = p;
                rk[i] = atomicAdd(&hist[p >> 16], 1);
            }
        }
        __syncthreads();
        int v = (hist[t] + 1) & ~1;    // even-rounded
        pre[t] = v;
        __syncthreads();
        for (int off = 1; off < 256; off <<= 1) {
            int u = (t >= off) ? pre[t - off] : 0;
            __syncthreads();
            pre[t] += u;
            __syncthreads();
        }
        const int myPre = pre[t] - v;
        const int gbase = (m * NBIN + bin) * BINCAP;
        const int node  = (bin << 8) | t;
        if (node < NN) {
            rowst[m * NN + node] = gbase + myPre;
            deg[m * NN + node]   = hist[t];
        }
        __syncthreads();
        pre[t] = myPre;
        __syncthreads();
#pragma unroll
        for (int i = 0; i < G2_EPT; i++) {
            if (rk[i] >= 0) {
                int d = (int)(pk[i] >> 16);
                int pos = pre[d] + rk[i];
                if (pos < BINCAP)
                    srcg[(size_t)gbase + pos] = (u16)(pk[i] & 0xffffu);
            }
        }
        return;
    }

    // ---- gemm path ----
    const int gb   = blockIdx.x - PART_NB;
    const int m    = gb / GEMM_NBX;
    const int bx   = gb - m * GEMM_NBX;
    const int lane = tid & 63, wid = tid >> 6;
    const int quad = lane >> 4, l16 = lane & 15;
    const int row0 = bx * 64 + wid * 16;

    {
        const uint4* gB = (const uint4*)(WgT + (size_t)m * DF * DIN);
#pragma unroll
        for (int it = 0; it < 16; ++it) {
            int c = it * 256 + tid;
            int r = c >> 4, k = c & 15;
            uint4 v = gB[c];
            *(uint4*)((char*)Bs + ((r * 16 + (k ^ (r & 7))) << 4)) = v;
        }
        const uint4* gW = (const uint4*)(WALT + (size_t)m * 16 * DIN);
        int c = tid;                     // 256 chunks = 4KB
        int r = c >> 4, k = c & 15;
        uint4 v = gW[c];
        *(uint4*)((char*)Bs + (BS_B_U16 * 2) + ((r * 16 + (k ^ (r & 7))) << 4)) = v;
    }
    __syncthreads();

    const int arow = row0 + l16;
    const int arc  = arow < NN ? arow : NN - 1;
    const u16* ab = hb + (size_t)arc * DIN + quad * 8;
    bf16x8 afrag[4];
#pragma unroll
    for (int ks = 0; ks < 4; ks++) afrag[ks] = *(const bf16x8*)(ab + ks * 32);

    f32x4 acc[16];
#pragma unroll
    for (int nt = 0; nt < 16; nt++) { acc[nt][0]=0.f; acc[nt][1]=0.f; acc[nt][2]=0.f; acc[nt][3]=0.f; }

#pragma unroll
    for (int nt = 0; nt < 16; nt++) {
        const int r = nt * 16 + l16;
        const int rbyte = r * 256;
        const int sw = (r & 7);
#pragma unroll
        for (int ks = 0; ks < 4; ks++) {
            int ck = (quad + 4 * ks) ^ sw;
            bf16x8 bfrag = *(const bf16x8*)((const char*)Bs + rbyte + (ck << 4));
            acc[nt] = __builtin_amdgcn_mfma_f32_16x16x32_bf16(afrag[ks], bfrag, acc[nt], 0, 0, 0);
        }
    }
    f32x4 acce; acce[0]=0.f; acce[1]=0.f; acce[2]=0.f; acce[3]=0.f;
    {
        const int r = l16;
        const int sw = (r & 7);
#pragma unroll
        for (int ks = 0; ks < 4; ks++) {
            int ck = (quad + 4 * ks) ^ sw;
            bf16x8 bfrag = *(const bf16x8*)((const char*)Bs + BS_B_U16 * 2 + r * 256 + (ck << 4));
            acce = __builtin_amdgcn_mfma_f32_16x16x32_bf16(afrag[ks], bfrag, acce, 0, 0, 0);
        }
    }
    const int rbase = row0 + quad * 4;
#pragma unroll
    for (int nt = 0; nt < 16; nt++)
#pragma unroll
        for (int r = 0; r < 4; r++) {
            int gr = rbase + r;
            if (gr < NN)
                feat[((size_t)m * NN + gr) * DF + nt * 16 + l16] = f2bf(acc[nt][r]);
        }
#pragma unroll
    for (int r = 0; r < 4; r++) {
        int gr = rbase + r;
        if (gr < NN) {
            if (l16 < 8) el[((size_t)m * NN + gr) * NH + l16]       = acce[r];
            else         er[((size_t)m * NN + gr) * NH + (l16 - 8)] = acce[r];
        }
    }
}

// ---------------------------------------------------------------------------
// 4) Destination-centric GAT, merged single dispatch (m = blockIdx.y).
// ---------------------------------------------------------------------------
__device__ __forceinline__ void edge_body(float x, float erm, float& sm,
                                          f32x2& A01, f32x2& A23, uint2 u)
{
    float tq = x + erm;
    tq = fmaxf(tq, 0.2f * tq);
    float w = __expf(tq);
    sm += w;
    f32x2 wv; wv.x = w; wv.y = w;
    A01 += wv * bfp(u.x);
    A23 += wv * bfp(u.y);
}

__global__ __launch_bounds__(256) void k_node(
    const u16* __restrict__ srcg, const int* __restrict__ rowst, const int* __restrict__ degA,
    const float* __restrict__ el, const float* __restrict__ er,
    const u16* __restrict__ feat, const float* __restrict__ bias, u16* __restrict__ z)
{
    const int lane = threadIdx.x & 63, wid = threadIdx.x >> 6;
    const int t = blockIdx.x * 4 + wid;
    const int m = blockIdx.y;
    if (t >= NN) return;
    const int idx  = m * NN + t;
    const int row0 = __builtin_amdgcn_readfirstlane(rowst[idx]);
    const int deg  = __builtin_amdgcn_readfirstlane(degA[idx]);
    const int kl   = lane >> 3;
    const int l4   = lane * 4;

    const float erm  = er[(size_t)idx * NH + kl];
    const float* elm = el + (size_t)m * NN * NH;
    const u16*   fm  = feat + (size_t)m * NN * DF;
    const u32*   cp  = (const u32*)(srcg + row0);   // row0 is even

    float sm = 0.f;
    f32x2 A01; A01.x = 0.f; A01.y = 0.f;
    f32x2 A23; A23.x = 0.f; A23.y = 0.f;

    int j = 0;
    for (; j + 16 <= deg; j += 16) {
        int s[16];
#pragma unroll
        for (int q = 0; q < 8; q++) {
            u32 u = __builtin_amdgcn_readfirstlane(cp[(j >> 1) + q]);
            s[2 * q]     = (int)(u & 0xffffu);
            s[2 * q + 1] = (int)(u >> 16);
        }
        float x[16];
#pragma unroll
        for (int q = 0; q < 16; q++) x[q] = elm[(size_t)s[q] * NH + kl];
        uint2 u[16];
#pragma unroll
        for (int q = 0; q < 16; q++) u[q] = *(const uint2*)(fm + (size_t)s[q] * DF + l4);
#pragma unroll
        for (int q = 0; q < 16; q++) edge_body(x[q], erm, sm, A01, A23, u[q]);
    }
    for (; j + 8 <= deg; j += 8) {
        int s[8];
#pragma unroll
        for (int q = 0; q < 4; q++) {
            u32 u = __builtin_amdgcn_readfirstlane(cp[(j >> 1) + q]);
            s[2 * q]     = (int)(u & 0xffffu);
            s[2 * q + 1] = (int)(u >> 16);
        }
        float x[8];
#pragma unroll
        for (int q = 0; q < 8; q++) x[q] = elm[(size_t)s[q] * NH + kl];
        uint2 u[8];
#pragma unroll
        for (int q = 0; q < 8; q++) u[q] = *(const uint2*)(fm + (size_t)s[q] * DF + l4);
#pragma unroll
        for (int q = 0; q < 8; q++) edge_body(x[q], erm, sm, A01, A23, u[q]);
    }
    for (; j + 2 <= deg; j += 2) {
        u32 up = __builtin_amdgcn_readfirstlane(cp[j >> 1]);
        int s0 = (int)(up & 0xffffu), s1 = (int)(up >> 16);
        float x0 = elm[(size_t)s0 * NH + kl];
        float x1 = elm[(size_t)s1 * NH + kl];
        uint2 u0 = *(const uint2*)(fm + (size_t)s0 * DF + l4);
        uint2 u1 = *(const uint2*)(fm + (size_t)s1 * DF + l4);
        edge_body(x0, erm, sm, A01, A23, u0);
        edge_body(x1, erm, sm, A01, A23, u1);
    }
    if (j < deg) {
        u32 up = __builtin_amdgcn_readfirstlane(cp[j >> 1]);
        int s0 = (int)(up & 0xffffu);
        float x = elm[(size_t)s0 * NH + kl];
        uint2 u = *(const uint2*)(fm + (size_t)s0 * DF + l4);
        edge_body(x, erm, sm, A01, A23, u);
    }
    const float rdm = 1.f / (sm + 1e-9f);

    float4 ub = *(const float4*)(bias + m * DF + l4);
    float z0 = A01.x * rdm + ub.x, z1 = A01.y * rdm + ub.y;
    float z2 = A23.x * rdm + ub.z, z3 = A23.y * rdm + ub.w;
    z0 = z0 > 0.f ? z0 : __expf(z0) - 1.f;
    z1 = z1 > 0.f ? z1 : __expf(z1) - 1.f;
    z2 = z2 > 0.f ? z2 : __expf(z2) - 1.f;
    z3 = z3 > 0.f ? z3 : __expf(z3) - 1.f;
    uint2 o;
    o.x = (u32)f2bf(z0) | ((u32)f2bf(z1) << 16);
    o.y = (u32)f2bf(z2) | ((u32)f2bf(z3) << 16);
    *(uint2*)(z + ((size_t)m * NN + t) * DF + l4) = o;
}

// ---------------------------------------------------------------------------
// 5) Semantic attention logits (R10 form: single 64-row group per block).
// ---------------------------------------------------------------------------
#define NSEM_NB ((NC + 63) / 64)   // 2344
__global__ __launch_bounds__(256) void k_sem(
    const u16* __restrict__ z, const u16* __restrict__ W1T,
    const float* __restrict__ b1, const float* __restrict__ w2,
    float* __restrict__ wpart)
{
    __shared__ __align__(16) u16 Ws[HID * DF];   // 64KB -> 2 blocks/CU
    __shared__ float buck[MP];
    const int tid = threadIdx.x, lane = tid & 63, wid = tid >> 6;
    const int quad = lane >> 4, l16 = lane & 15;
    if (tid < MP) buck[tid] = 0.f;

    {   // stage W1T: 128 rows x 32 chunks(16B) = 4096 chunks
        const uint4* gW = (const uint4*)W1T;
#pragma unroll
        for (int it = 0; it < 16; ++it) {
            int c = it * 256 + tid;
            int r = c >> 5, k = c & 31;
            uint4 v = gW[c];
            *(uint4*)((char*)Ws + ((r * 32 + (k ^ (r & 7))) << 4)) = v;
        }
    }
    __syncthreads();

    const int row0 = blockIdx.x * 64 + wid * 16;
    const int arow = row0 + l16;
    const int arc  = arow < NC ? arow : NC - 1;
    const u16* ab = z + (size_t)arc * DF + quad * 8;
    bf16x8 afrag[8];
#pragma unroll
    for (int ks = 0; ks < 8; ks++) afrag[ks] = *(const bf16x8*)(ab + ks * 32);

    float rsum[4] = {0.f, 0.f, 0.f, 0.f};
#pragma unroll
    for (int nt = 0; nt < 8; nt++) {
        f32x4 acc; acc[0]=0.f; acc[1]=0.f; acc[2]=0.f; acc[3]=0.f;
        const int r = nt * 16 + l16;
        const int rbyte = r * 512;
        const int sw = (r & 7);
#pragma unroll
        for (int ks = 0; ks < 8; ks++) {
            int ck = (quad + 4 * ks) ^ sw;
            bf16x8 bfrag = *(const bf16x8*)((const char*)Ws + rbyte + (ck << 4));
            acc = __builtin_amdgcn_mfma_f32_16x16x32_bf16(afrag[ks], bfrag, acc, 0, 0, 0);
        }
        const int col = nt * 16 + l16;
        const float bb1 = b1[col], ww2 = w2[col];
#pragma unroll
        for (int r2 = 0; r2 < 4; r2++) rsum[r2] += tanh_fast(acc[r2] + bb1) * ww2;
    }
#pragma unroll
    for (int msk = 1; msk <= 8; msk <<= 1)
#pragma unroll
        for (int r = 0; r < 4; r++) rsum[r] += __shfl_xor(rsum[r], msk);

    if (l16 == 0) {
#pragma unroll
        for (int r = 0; r < 4; r++) {
            int g = row0 + quad * 4 + r;
            if (g < NC) atomicAdd(&buck[g / NN], rsum[r]);   // LDS atomic: fast
        }
    }
    __syncthreads();
    if (tid < MP) wpart[(size_t)blockIdx.x * 4 + tid] = buck[tid];
}

// ---------------------------------------------------------------------------
// 6) k_combine with inlined beta: every block redundantly reduces wpart
//    (28KB L2-broadcast, deterministic order -> identical beta) then streams.
//    Kills the k_beta launch.
// ---------------------------------------------------------------------------
__global__ __launch_bounds__(256) void k_combine(
    const u16* __restrict__ z, const float* __restrict__ wpart, float* __restrict__ out)
{
    __shared__ float r0[256], r1[256], r2[256];
    __shared__ float bsh[4];
    const int tid = threadIdx.x;
    {
        float s0 = 0.f, s1 = 0.f, s2 = 0.f;
        for (int i = tid; i < NSEM_NB; i += 256) {
            s0 += wpart[(size_t)i * 4 + 0];
            s1 += wpart[(size_t)i * 4 + 1];
            s2 += wpart[(size_t)i * 4 + 2];
        }
        r0[tid] = s0; r1[tid] = s1; r2[tid] = s2;
        __syncthreads();
        for (int off = 128; off > 0; off >>= 1) {
            if (tid < off) {
                r0[tid] += r0[tid + off];
                r1[tid] += r1[tid + off];
                r2[tid] += r2[tid + off];
            }
            __syncthreads();
        }
        if (tid == 0) {
            float w0 = r0[0] / (float)NN, w1 = r1[0] / (float)NN, w2v = r2[0] / (float)NN;
            float mx = fmaxf(w0, fmaxf(w1, w2v));
            float e0 = expf(w0 - mx), e1 = expf(w1 - mx), e2 = expf(w2v - mx);
            float s = e0 + e1 + e2;
            bsh[0] = e0 / s; bsh[1] = e1 / s; bsh[2] = e2 / s;
        }
        __syncthreads();
    }
    const float b0 = bsh[0], b1 = bsh[1], b2 = bsh[2];

    size_t i = ((size_t)blockIdx.x * 256 + tid) * 8;
    if (i >= (size_t)NN * DF) return;
    uint4 u0 = *(const uint4*)(z + i);
    uint4 u1 = *(const uint4*)(z + (size_t)NN * DF + i);
    uint4 u2 = *(const uint4*)(z + 2 * (size_t)NN * DF + i);
    float4 oa, ob;
    oa.x = b0 * bf2f((u16)(u0.x & 0xffff)) + b1 * bf2f((u16)(u1.x & 0xffff)) + b2 * bf2f((u16)(u2.x & 0xffff));
    oa.y = b0 * bf2f((u16)(u0.x >> 16))    + b1 * bf2f((u16)(u1.x >> 16))    + b2 * bf2f((u16)(u2.x >> 16));
    oa.z = b0 * bf2f((u16)(u0.y & 0xffff)) + b1 * bf2f((u16)(u1.y & 0xffff)) + b2 * bf2f((u16)(u2.y & 0xffff));
    oa.w = b0 * bf2f((u16)(u0.y >> 16))    + b1 * bf2f((u16)(u1.y >> 16))    + b2 * bf2f((u16)(u2.y >> 16));
    ob.x = b0 * bf2f((u16)(u0.z & 0xffff)) + b1 * bf2f((u16)(u1.z & 0xffff)) + b2 * bf2f((u16)(u2.z & 0xffff));
    ob.y = b0 * bf2f((u16)(u0.z >> 16))    + b1 * bf2f((u16)(u1.z >> 16))    + b2 * bf2f((u16)(u2.z >> 16));
    ob.z = b0 * bf2f((u16)(u0.w & 0xffff)) + b1 * bf2f((u16)(u1.w & 0xffff)) + b2 * bf2f((u16)(u2.w & 0xffff));
    ob.w = b0 * bf2f((u16)(u0.w >> 16))    + b1 * bf2f((u16)(u1.w >> 16))    + b2 * bf2f((u16)(u2.w >> 16));
    *(float4*)(out + i) = oa;
    *(float4*)(out + i + 4) = ob;
}

// ---------------------------------------------------------------------------
extern "C" void kernel_launch(void* const* d_in, const int* in_sizes, int n_in,
                              void* d_out, int out_size, void* d_ws, size_t ws_size,
                              hipStream_t stream)
{
    const float* h    = (const float*)d_in[0];
    const float* Wg   = (const float*)d_in[1];
    const float* al   = (const float*)d_in[2];
    const float* ar   = (const float*)d_in[3];
    const float* bias = (const float*)d_in[4];
    const float* W1   = (const float*)d_in[5];
    const float* b1   = (const float*)d_in[6];
    const float* w2   = (const float*)d_in[7];
    const int*   src  = (const int*)d_in[8];
    const int*   dst  = (const int*)d_in[9];
    float* out = (float*)d_out;

    char* w = (char*)d_ws;
    size_t off = 0;
    auto take = [&](size_t b) -> char* {
        char* p = w + off;
        off = (off + b + 255) & ~(size_t)255;
        return p;
    };
    u16*   feat    = (u16*)  take((size_t)MP * NN * DF * 2);
    u16*   zbuf    = (u16*)  take((size_t)MP * NN * DF * 2);
    u16*   hb      = (u16*)  take((size_t)NN * DIN * 2);
    u16*   WgT     = (u16*)  take((size_t)MP * DF * DIN * 2);
    u16*   W1T     = (u16*)  take((size_t)HID * DF * 2);
    u16*   WALT    = (u16*)  take((size_t)MP * 16 * DIN * 2);
    float* el      = (float*)take((size_t)MP * NN * NH * 4);
    float* er      = (float*)take((size_t)MP * NN * NH * 4);
    int*   binCnt  = (int*)  take((size_t)MP * NBIN * 4);
    u32*   part    = (u32*)  take((size_t)MP * NBIN * BINCAP * 4);  // 12.0 MB
    u16*   srcg    = (u16*)  take((size_t)MP * NBIN * BINCAP * 2);  // 6.0 MB
    int*   rowst   = (int*)  take((size_t)NC * 4);
    int*   deg     = (int*)  take((size_t)NC * 4);
    float* wpart   = (float*)take((size_t)NSEM_NB * 4 * 4);

    hipMemsetAsync(binCnt, 0, (size_t)MP * NBIN * 4, stream);

    k_part_cvt<<<PC_NB, 256, 0, stream>>>(
        src, dst, binCnt, part, h, Wg, W1, al, ar, hb, WgT, W1T, WALT);
    k_group_gemm<<<GG_NB, 256, 0, stream>>>(
        binCnt, part, srcg, rowst, deg, hb, WgT, WALT, feat, el, er);
    k_node<<<dim3((NN + 3) / 4, MP), 256, 0, stream>>>(srcg, rowst, deg, el, er, feat, bias, zbuf);
    k_sem<<<NSEM_NB, 256, 0, stream>>>(zbuf, W1T, b1, w2, wpart);
    k_combine<<<(NN * DF / 8 + 255) / 256, 256, 0, stream>>>(zbuf, wpart, out);
}

// Round 14
// 414.398 us; speedup vs baseline: 1.0119x; 1.0119x over previous
//
#include <hip/hip_runtime.h>
#include <hip/hip_bf16.h>

#define NN   50000
#define NE   800000
#define MP   3
#define DIN  128
#define DF   256     // HEADS*OUT_DIM
#define NH   8
#define HID  128
#define NC   (MP*NN)              // 150000

#define NBIN   196                // bin = dst >> 8
#define BINCAP 5120               // >=16 sigma above Poisson mean 4082
#define G1_EPB 4096               // edges per k_part block
#define G1_EPT (G1_EPB / 256)     // 16
#define G1_NB  ((NE + G1_EPB - 1) / G1_EPB)   // 196
#define G2_EPT (BINCAP / 256)     // 20

typedef unsigned short u16;
typedef unsigned int   u32;
typedef __attribute__((ext_vector_type(8))) short bf16x8;   // MFMA A/B frag
typedef __attribute__((ext_vector_type(4))) float f32x4;    // MFMA C/D frag
typedef __attribute__((ext_vector_type(2))) float f32x2;    // pk-math pair

__device__ __forceinline__ float bf2f(u16 u) {
    return __uint_as_float(((u32)u) << 16);
}
__device__ __forceinline__ u16 f2bf(float f) {
    u32 x = __float_as_uint(f);
    u32 r = x + 0x7fffu + ((x >> 16) & 1u);   // round-to-nearest-even
    return (u16)(r >> 16);
}
__device__ __forceinline__ f32x2 bfp(u32 u) {   // unpack bf16 pair -> f32x2
    f32x2 r;
    r.x = __uint_as_float(u << 16);
    r.y = __uint_as_float(u & 0xffff0000u);
    return r;
}
__device__ __forceinline__ float tanh_fast(float x) {
    float c = fminf(fmaxf(x, -15.f), 15.f);
    float t = __expf(2.f * c);
    return (t - 1.f) / (t + 1.f);
}

// ---------------------------------------------------------------------------
// 0) FUSED k_part + k_cvt (R12 measured-best). Partition blocks [0, MP*G1_NB):
//    LDS-atomic ranks, one device atomic per (block,bin). Conversion blocks
//    behind: h->hb, Wg->WgT, W1->W1T, WAL->WALT.
// ---------------------------------------------------------------------------
#define CVT_H_N   (NN * DIN / 8)          // 800000
#define CVT_WG_N  (MP * DF * DIN)         // 98304
#define CVT_W1_N  (HID * DF)              // 32768
#define CVT_WAL_N (MP * 16 * DIN)         // 6144
#define CVT_TOT_N (CVT_H_N + CVT_WG_N + CVT_W1_N + CVT_WAL_N)   // 937216
#define CVT_NB    ((CVT_TOT_N + 255) / 256)                     // 3661
#define PART_NB   (MP * G1_NB)                                  // 588
#define PC_NB     (PART_NB + CVT_NB)                            // 4249
__global__ __launch_bounds__(256) void k_part_cvt(
    const int* __restrict__ src, const int* __restrict__ dst,
    int* __restrict__ binCnt, u32* __restrict__ part,
    const float* __restrict__ h, const float* __restrict__ Wg, const float* __restrict__ W1,
    const float* __restrict__ al, const float* __restrict__ ar,
    u16* __restrict__ hb, u16* __restrict__ WgT, u16* __restrict__ W1T, u16* __restrict__ WALT)
{
    __shared__ int hist[NBIN];
    __shared__ int base[NBIN];
    const int t = threadIdx.x;
    if (blockIdx.x < PART_NB) {   // ---- partition path ----
        const int m  = blockIdx.x / G1_NB;
        const int bx = blockIdx.x - m * G1_NB;
        if (t < NBIN) hist[t] = 0;
        __syncthreads();

        const int e0 = bx * G1_EPB;
        u32 pk[G1_EPT];
        int bn[G1_EPT];
        int rk[G1_EPT];
#pragma unroll
        for (int i = 0; i < G1_EPT; i++) {
            int e = e0 + i * 256 + t;
            bn[i] = -1;
            if (e < NE) {
                int d = dst[(size_t)m * NE + e];
                int s = src[(size_t)m * NE + e];
                bn[i] = d >> 8;
                pk[i] = (u32)s | ((u32)(d & 255) << 16);
                rk[i] = atomicAdd(&hist[bn[i]], 1);
            }
        }
        __syncthreads();
        if (t < NBIN)
            base[t] = hist[t] > 0 ? atomicAdd(&binCnt[m * NBIN + t], hist[t]) : 0;
        __syncthreads();
#pragma unroll
        for (int i = 0; i < G1_EPT; i++) {
            if (bn[i] >= 0) {
                int pos = base[bn[i]] + rk[i];
                if (pos < BINCAP)
                    part[((size_t)(m * NBIN + bn[i])) * BINCAP + pos] = pk[i];
            }
        }
        return;
    }
    // ---- conversion path ----
    int gid = (blockIdx.x - PART_NB) * 256 + t;
    if (gid < CVT_H_N) {
        size_t i8 = (size_t)gid * 8;
        float4 a = *(const float4*)(h + i8);
        float4 b = *(const float4*)(h + i8 + 4);
        uint4 o;
        o.x = (u32)f2bf(a.x) | ((u32)f2bf(a.y) << 16);
        o.y = (u32)f2bf(a.z) | ((u32)f2bf(a.w) << 16);
        o.z = (u32)f2bf(b.x) | ((u32)f2bf(b.y) << 16);
        o.w = (u32)f2bf(b.z) | ((u32)f2bf(b.w) << 16);
        *(uint4*)(hb + i8) = o;
    } else if (gid < CVT_H_N + CVT_WG_N) {
        int g = gid - CVT_H_N;
        int k = g % DIN, n = (g / DIN) % DF, m = g / (DIN * DF);
        WgT[g] = f2bf(Wg[((size_t)m * DIN + k) * DF + n]);
    } else if (gid < CVT_H_N + CVT_WG_N + CVT_W1_N) {
        int g = gid - CVT_H_N - CVT_WG_N;
        int k = g % DF, n = g / DF;
        W1T[g] = f2bf(W1[(size_t)k * HID + n]);
    } else if (gid < CVT_TOT_N) {
        int g = gid - CVT_H_N - CVT_WG_N - CVT_W1_N;
        int k = g & (DIN - 1), c = (g >> 7) & 15, m = g >> 11;
        int hh = c & 7;
        const float* a  = (c < 8 ? al : ar) + ((size_t)m * NH + hh) * 32;
        const float* wg = Wg + ((size_t)m * DIN + k) * DF + 32 * hh;
        float s = 0.f;
#pragma unroll
        for (int d = 0; d < 32; d++) s += wg[d] * a[d];
        WALT[g] = f2bf(s);
    }
}

// ---------------------------------------------------------------------------
// 0c) k_group: one block per (m,bin) -> true CSR (u16 src groups, rowst/deg).
//     Separate dispatch (R13's fusion into gemm cost LDS co-residency).
// ---------------------------------------------------------------------------
__global__ __launch_bounds__(256) void k_group(
    const int* __restrict__ binCnt, const u32* __restrict__ part,
    u16* __restrict__ srcg, int* __restrict__ rowst, int* __restrict__ deg)
{
    __shared__ int hist[256];
    __shared__ int pre[256];
    const int bin = blockIdx.x, m = blockIdx.y;
    const int t = threadIdx.x;
    hist[t] = 0;
    __syncthreads();

    int cnt = binCnt[m * NBIN + bin];
    cnt = cnt < BINCAP ? cnt : BINCAP;
    const u32* pp = part + ((size_t)(m * NBIN + bin)) * BINCAP;

    u32 pk[G2_EPT];
    int rk[G2_EPT];
#pragma unroll
    for (int i = 0; i < G2_EPT; i++) {
        int j = i * 256 + t;
        rk[i] = -1;
        if (j < cnt) {
            u32 p = pp[j];
            pk[i] = p;
            rk[i] = atomicAdd(&hist[p >> 16], 1);
        }
    }
    __syncthreads();
    int v = (hist[t] + 1) & ~1;    // even-rounded
    pre[t] = v;
    __syncthreads();
    for (int off = 1; off < 256; off <<= 1) {
        int u = (t >= off) ? pre[t - off] : 0;
        __syncthreads();
        pre[t] += u;
        __syncthreads();
    }
    const int myPre = pre[t] - v;
    const int gbase = (m * NBIN + bin) * BINCAP;
    const int node  = (bin << 8) | t;
    if (node < NN) {
        rowst[m * NN + node] = gbase + myPre;
        deg[m * NN + node]   = hist[t];
    }
    __syncthreads();
    pre[t] = myPre;
    __syncthreads();
#pragma unroll
    for (int i = 0; i < G2_EPT; i++) {
        if (rk[i] >= 0) {
            int d = (int)(pk[i] >> 16);
            int pos = pre[d] + rk[i];
            if (pos < BINCAP)
                srcg[(size_t)gbase + pos] = (u16)(pk[i] & 0xffffu);
        }
    }
}

// ---------------------------------------------------------------------------
// 1) feat[m] = h @ W_gat[m]. LDS-staged B-panel (64KB WgT + 4KB WALT),
//    XOR swizzle (chunk ^= row&7). Separate dispatch.
// ---------------------------------------------------------------------------
#define BS_B_U16 (DF * DIN)        // 32768 u16 = 64KB
__global__ __launch_bounds__(256) void k_gemm_feat(
    const u16* __restrict__ hb, const u16* __restrict__ WgT, const u16* __restrict__ WALT,
    u16* __restrict__ feat, float* __restrict__ el, float* __restrict__ er)
{
    __shared__ __align__(16) u16 Bs[BS_B_U16 + 16 * DIN];   // 68KB -> 2 blocks/CU
    const int tid = threadIdx.x, lane = tid & 63, wid = tid >> 6;
    const int quad = lane >> 4, l16 = lane & 15;
    const int m    = blockIdx.y;
    const int row0 = blockIdx.x * 64 + wid * 16;

    {
        const uint4* gB = (const uint4*)(WgT + (size_t)m * DF * DIN);
#pragma unroll
        for (int it = 0; it < 16; ++it) {
            int c = it * 256 + tid;
            int r = c >> 4, k = c & 15;
            uint4 v = gB[c];
            *(uint4*)((char*)Bs + ((r * 16 + (k ^ (r & 7))) << 4)) = v;
        }
        const uint4* gW = (const uint4*)(WALT + (size_t)m * 16 * DIN);
        int c = tid;                     // 256 chunks = 4KB
        int r = c >> 4, k = c & 15;
        uint4 v = gW[c];
        *(uint4*)((char*)Bs + (BS_B_U16 * 2) + ((r * 16 + (k ^ (r & 7))) << 4)) = v;
    }
    __syncthreads();

    const int arow = row0 + l16;
    const int arc  = arow < NN ? arow : NN - 1;
    const u16* ab = hb + (size_t)arc * DIN + quad * 8;
    bf16x8 afrag[4];
#pragma unroll
    for (int ks = 0; ks < 4; ks++) afrag[ks] = *(const bf16x8*)(ab + ks * 32);

    f32x4 acc[16];
#pragma unroll
    for (int nt = 0; nt < 16; nt++) { acc[nt][0]=0.f; acc[nt][1]=0.f; acc[nt][2]=0.f; acc[nt][3]=0.f; }

#pragma unroll
    for (int nt = 0; nt < 16; nt++) {
        const int r = nt * 16 + l16;
        const int rbyte = r * 256;
        const int sw = (r & 7);
#pragma unroll
        for (int ks = 0; ks < 4; ks++) {
            int ck = (quad + 4 * ks) ^ sw;
            bf16x8 bfrag = *(const bf16x8*)((const char*)Bs + rbyte + (ck << 4));
            acc[nt] = __builtin_amdgcn_mfma_f32_16x16x32_bf16(afrag[ks], bfrag, acc[nt], 0, 0, 0);
        }
    }
    f32x4 acce; acce[0]=0.f; acce[1]=0.f; acce[2]=0.f; acce[3]=0.f;
    {
        const int r = l16;
        const int sw = (r & 7);
#pragma unroll
        for (int ks = 0; ks < 4; ks++) {
            int ck = (quad + 4 * ks) ^ sw;
            bf16x8 bfrag = *(const bf16x8*)((const char*)Bs + BS_B_U16 * 2 + r * 256 + (ck << 4));
            acce = __builtin_amdgcn_mfma_f32_16x16x32_bf16(afrag[ks], bfrag, acce, 0, 0, 0);
        }
    }
    const int rbase = row0 + quad * 4;
#pragma unroll
    for (int nt = 0; nt < 16; nt++)
#pragma unroll
        for (int r = 0; r < 4; r++) {
            int gr = rbase + r;
            if (gr < NN)
                feat[((size_t)m * NN + gr) * DF + nt * 16 + l16] = f2bf(acc[nt][r]);
        }
#pragma unroll
    for (int r = 0; r < 4; r++) {
        int gr = rbase + r;
        if (gr < NN) {
            if (l16 < 8) el[((size_t)m * NN + gr) * NH + l16]       = acce[r];
            else         er[((size_t)m * NN + gr) * NH + (l16 - 8)] = acce[r];
        }
    }
}

// ---------------------------------------------------------------------------
// 4) Destination-centric GAT, merged single dispatch (m = blockIdx.y).
// ---------------------------------------------------------------------------
__device__ __forceinline__ void edge_body(float x, float erm, float& sm,
                                          f32x2& A01, f32x2& A23, uint2 u)
{
    float tq = x + erm;
    tq = fmaxf(tq, 0.2f * tq);
    float w = __expf(tq);
    sm += w;
    f32x2 wv; wv.x = w; wv.y = w;
    A01 += wv * bfp(u.x);
    A23 += wv * bfp(u.y);
}

__global__ __launch_bounds__(256) void k_node(
    const u16* __restrict__ srcg, const int* __restrict__ rowst, const int* __restrict__ degA,
    const float* __restrict__ el, const float* __restrict__ er,
    const u16* __restrict__ feat, const float* __restrict__ bias, u16* __restrict__ z)
{
    const int lane = threadIdx.x & 63, wid = threadIdx.x >> 6;
    const int t = blockIdx.x * 4 + wid;
    const int m = blockIdx.y;
    if (t >= NN) return;
    const int idx  = m * NN + t;
    const int row0 = __builtin_amdgcn_readfirstlane(rowst[idx]);
    const int deg  = __builtin_amdgcn_readfirstlane(degA[idx]);
    const int kl   = lane >> 3;
    const int l4   = lane * 4;

    const float erm  = er[(size_t)idx * NH + kl];
    const float* elm = el + (size_t)m * NN * NH;
    const u16*   fm  = feat + (size_t)m * NN * DF;
    const u32*   cp  = (const u32*)(srcg + row0);   // row0 is even

    float sm = 0.f;
    f32x2 A01; A01.x = 0.f; A01.y = 0.f;
    f32x2 A23; A23.x = 0.f; A23.y = 0.f;

    int j = 0;
    for (; j + 16 <= deg; j += 16) {
        int s[16];
#pragma unroll
        for (int q = 0; q < 8; q++) {
            u32 u = __builtin_amdgcn_readfirstlane(cp[(j >> 1) + q]);
            s[2 * q]     = (int)(u & 0xffffu);
            s[2 * q + 1] = (int)(u >> 16);
        }
        float x[16];
#pragma unroll
        for (int q = 0; q < 16; q++) x[q] = elm[(size_t)s[q] * NH + kl];
        uint2 u[16];
#pragma unroll
        for (int q = 0; q < 16; q++) u[q] = *(const uint2*)(fm + (size_t)s[q] * DF + l4);
#pragma unroll
        for (int q = 0; q < 16; q++) edge_body(x[q], erm, sm, A01, A23, u[q]);
    }
    for (; j + 8 <= deg; j += 8) {
        int s[8];
#pragma unroll
        for (int q = 0; q < 4; q++) {
            u32 u = __builtin_amdgcn_readfirstlane(cp[(j >> 1) + q]);
            s[2 * q]     = (int)(u & 0xffffu);
            s[2 * q + 1] = (int)(u >> 16);
        }
        float x[8];
#pragma unroll
        for (int q = 0; q < 8; q++) x[q] = elm[(size_t)s[q] * NH + kl];
        uint2 u[8];
#pragma unroll
        for (int q = 0; q < 8; q++) u[q] = *(const uint2*)(fm + (size_t)s[q] * DF + l4);
#pragma unroll
        for (int q = 0; q < 8; q++) edge_body(x[q], erm, sm, A01, A23, u[q]);
    }
    for (; j + 2 <= deg; j += 2) {
        u32 up = __builtin_amdgcn_readfirstlane(cp[j >> 1]);
        int s0 = (int)(up & 0xffffu), s1 = (int)(up >> 16);
        float x0 = elm[(size_t)s0 * NH + kl];
        float x1 = elm[(size_t)s1 * NH + kl];
        uint2 u0 = *(const uint2*)(fm + (size_t)s0 * DF + l4);
        uint2 u1 = *(const uint2*)(fm + (size_t)s1 * DF + l4);
        edge_body(x0, erm, sm, A01, A23, u0);
        edge_body(x1, erm, sm, A01, A23, u1);
    }
    if (j < deg) {
        u32 up = __builtin_amdgcn_readfirstlane(cp[j >> 1]);
        int s0 = (int)(up & 0xffffu);
        float x = elm[(size_t)s0 * NH + kl];
        uint2 u = *(const uint2*)(fm + (size_t)s0 * DF + l4);
        edge_body(x, erm, sm, A01, A23, u);
    }
    const float rdm = 1.f / (sm + 1e-9f);

    float4 ub = *(const float4*)(bias + m * DF + l4);
    float z0 = A01.x * rdm + ub.x, z1 = A01.y * rdm + ub.y;
    float z2 = A23.x * rdm + ub.z, z3 = A23.y * rdm + ub.w;
    z0 = z0 > 0.f ? z0 : __expf(z0) - 1.f;
    z1 = z1 > 0.f ? z1 : __expf(z1) - 1.f;
    z2 = z2 > 0.f ? z2 : __expf(z2) - 1.f;
    z3 = z3 > 0.f ? z3 : __expf(z3) - 1.f;
    uint2 o;
    o.x = (u32)f2bf(z0) | ((u32)f2bf(z1) << 16);
    o.y = (u32)f2bf(z2) | ((u32)f2bf(z3) << 16);
    *(uint2*)(z + ((size_t)m * NN + t) * DF + l4) = o;
}

// ---------------------------------------------------------------------------
// 5) Semantic attention logits (R10 form: single 64-row group per block).
// ---------------------------------------------------------------------------
#define NSEM_NB ((NC + 63) / 64)   // 2344
__global__ __launch_bounds__(256) void k_sem(
    const u16* __restrict__ z, const u16* __restrict__ W1T,
    const float* __restrict__ b1, const float* __restrict__ w2,
    float* __restrict__ wpart)
{
    __shared__ __align__(16) u16 Ws[HID * DF];   // 64KB -> 2 blocks/CU
    __shared__ float buck[MP];
    const int tid = threadIdx.x, lane = tid & 63, wid = tid >> 6;
    const int quad = lane >> 4, l16 = lane & 15;
    if (tid < MP) buck[tid] = 0.f;

    {   // stage W1T: 128 rows x 32 chunks(16B) = 4096 chunks
        const uint4* gW = (const uint4*)W1T;
#pragma unroll
        for (int it = 0; it < 16; ++it) {
            int c = it * 256 + tid;
            int r = c >> 5, k = c & 31;
            uint4 v = gW[c];
            *(uint4*)((char*)Ws + ((r * 32 + (k ^ (r & 7))) << 4)) = v;
        }
    }
    __syncthreads();

    const int row0 = blockIdx.x * 64 + wid * 16;
    const int arow = row0 + l16;
    const int arc  = arow < NC ? arow : NC - 1;
    const u16* ab = z + (size_t)arc * DF + quad * 8;
    bf16x8 afrag[8];
#pragma unroll
    for (int ks = 0; ks < 8; ks++) afrag[ks] = *(const bf16x8*)(ab + ks * 32);

    float rsum[4] = {0.f, 0.f, 0.f, 0.f};
#pragma unroll
    for (int nt = 0; nt < 8; nt++) {
        f32x4 acc; acc[0]=0.f; acc[1]=0.f; acc[2]=0.f; acc[3]=0.f;
        const int r = nt * 16 + l16;
        const int rbyte = r * 512;
        const int sw = (r & 7);
#pragma unroll
        for (int ks = 0; ks < 8; ks++) {
            int ck = (quad + 4 * ks) ^ sw;
            bf16x8 bfrag = *(const bf16x8*)((const char*)Ws + rbyte + (ck << 4));
            acc = __builtin_amdgcn_mfma_f32_16x16x32_bf16(afrag[ks], bfrag, acc, 0, 0, 0);
        }
        const int col = nt * 16 + l16;
        const float bb1 = b1[col], ww2 = w2[col];
#pragma unroll
        for (int r2 = 0; r2 < 4; r2++) rsum[r2] += tanh_fast(acc[r2] + bb1) * ww2;
    }
#pragma unroll
    for (int msk = 1; msk <= 8; msk <<= 1)
#pragma unroll
        for (int r = 0; r < 4; r++) rsum[r] += __shfl_xor(rsum[r], msk);

    if (l16 == 0) {
#pragma unroll
        for (int r = 0; r < 4; r++) {
            int g = row0 + quad * 4 + r;
            if (g < NC) atomicAdd(&buck[g / NN], rsum[r]);   // LDS atomic: fast
        }
    }
    __syncthreads();
    if (tid < MP) wpart[(size_t)blockIdx.x * 4 + tid] = buck[tid];
}

__global__ __launch_bounds__(256) void k_beta(const float* __restrict__ wpart, float* __restrict__ beta) {
    __shared__ float r0[256], r1[256], r2[256];
    const int tid = threadIdx.x;
    float s0 = 0.f, s1 = 0.f, s2 = 0.f;
    for (int i = tid; i < NSEM_NB; i += 256) {
        s0 += wpart[(size_t)i * 4 + 0];
        s1 += wpart[(size_t)i * 4 + 1];
        s2 += wpart[(size_t)i * 4 + 2];
    }
    r0[tid] = s0; r1[tid] = s1; r2[tid] = s2;
    __syncthreads();
    for (int off = 128; off > 0; off >>= 1) {
        if (tid < off) {
            r0[tid] += r0[tid + off];
            r1[tid] += r1[tid + off];
            r2[tid] += r2[tid + off];
        }
        __syncthreads();
    }
    if (tid == 0) {
        float w0 = r0[0] / (float)NN, w1 = r1[0] / (float)NN, w2v = r2[0] / (float)NN;
        float mx = fmaxf(w0, fmaxf(w1, w2v));
        float e0 = expf(w0 - mx), e1 = expf(w1 - mx), e2 = expf(w2v - mx);
        float s = e0 + e1 + e2;
        beta[0] = e0 / s; beta[1] = e1 / s; beta[2] = e2 / s;
    }
}

__global__ __launch_bounds__(256) void k_combine(
    const u16* __restrict__ z, const float* __restrict__ beta, float* __restrict__ out)
{
    size_t i = ((size_t)blockIdx.x * 256 + threadIdx.x) * 8;
    if (i >= (size_t)NN * DF) return;
    float b0 = beta[0], b1 = beta[1], b2 = beta[2];
    uint4 u0 = *(const uint4*)(z + i);
    uint4 u1 = *(const uint4*)(z + (size_t)NN * DF + i);
    uint4 u2 = *(const uint4*)(z + 2 * (size_t)NN * DF + i);
    float4 oa, ob;
    oa.x = b0 * bf2f((u16)(u0.x & 0xffff)) + b1 * bf2f((u16)(u1.x & 0xffff)) + b2 * bf2f((u16)(u2.x & 0xffff));
    oa.y = b0 * bf2f((u16)(u0.x >> 16))    + b1 * bf2f((u16)(u1.x >> 16))    + b2 * bf2f((u16)(u2.x >> 16));
    oa.z = b0 * bf2f((u16)(u0.y & 0xffff)) + b1 * bf2f((u16)(u1.y & 0xffff)) + b2 * bf2f((u16)(u2.y & 0xffff));
    oa.w = b0 * bf2f((u16)(u0.y >> 16))    + b1 * bf2f((u16)(u1.y >> 16))    + b2 * bf2f((u16)(u2.y >> 16));
    ob.x = b0 * bf2f((u16)(u0.z & 0xffff)) + b1 * bf2f((u16)(u1.z & 0xffff)) + b2 * bf2f((u16)(u2.z & 0xffff));
    ob.y = b0 * bf2f((u16)(u0.z >> 16))    + b1 * bf2f((u16)(u1.z >> 16))    + b2 * bf2f((u16)(u2.z >> 16));
    ob.z = b0 * bf2f((u16)(u0.w & 0xffff)) + b1 * bf2f((u16)(u1.w & 0xffff)) + b2 * bf2f((u16)(u2.w & 0xffff));
    ob.w = b0 * bf2f((u16)(u0.w >> 16))    + b1 * bf2f((u16)(u1.w >> 16))    + b2 * bf2f((u16)(u2.w >> 16));
    *(float4*)(out + i) = oa;
    *(float4*)(out + i + 4) = ob;
}

// ---------------------------------------------------------------------------
extern "C" void kernel_launch(void* const* d_in, const int* in_sizes, int n_in,
                              void* d_out, int out_size, void* d_ws, size_t ws_size,
                              hipStream_t stream)
{
    const float* h    = (const float*)d_in[0];
    const float* Wg   = (const float*)d_in[1];
    const float* al   = (const float*)d_in[2];
    const float* ar   = (const float*)d_in[3];
    const float* bias = (const float*)d_in[4];
    const float* W1   = (const float*)d_in[5];
    const float* b1   = (const float*)d_in[6];
    const float* w2   = (const float*)d_in[7];
    const int*   src  = (const int*)d_in[8];
    const int*   dst  = (const int*)d_in[9];
    float* out = (float*)d_out;

    char* w = (char*)d_ws;
    size_t off = 0;
    auto take = [&](size_t b) -> char* {
        char* p = w + off;
        off = (off + b + 255) & ~(size_t)255;
        return p;
    };
    u16*   feat    = (u16*)  take((size_t)MP * NN * DF * 2);
    u16*   zbuf    = (u16*)  take((size_t)MP * NN * DF * 2);
    u16*   hb      = (u16*)  take((size_t)NN * DIN * 2);
    u16*   WgT     = (u16*)  take((size_t)MP * DF * DIN * 2);
    u16*   W1T     = (u16*)  take((size_t)HID * DF * 2);
    u16*   WALT    = (u16*)  take((size_t)MP * 16 * DIN * 2);
    float* el      = (float*)take((size_t)MP * NN * NH * 4);
    float* er      = (float*)take((size_t)MP * NN * NH * 4);
    int*   binCnt  = (int*)  take((size_t)MP * NBIN * 4);
    u32*   part    = (u32*)  take((size_t)MP * NBIN * BINCAP * 4);  // 12.0 MB
    u16*   srcg    = (u16*)  take((size_t)MP * NBIN * BINCAP * 2);  // 6.0 MB
    int*   rowst   = (int*)  take((size_t)NC * 4);
    int*   deg     = (int*)  take((size_t)NC * 4);
    float* wpart   = (float*)take((size_t)NSEM_NB * 4 * 4);
    float* beta    = (float*)take(64);

    hipMemsetAsync(binCnt, 0, (size_t)MP * NBIN * 4, stream);

    k_part_cvt<<<PC_NB, 256, 0, stream>>>(
        src, dst, binCnt, part, h, Wg, W1, al, ar, hb, WgT, W1T, WALT);
    k_group<<<dim3(NBIN, MP), 256, 0, stream>>>(binCnt, part, srcg, rowst, deg);
    k_gemm_feat<<<dim3((NN + 63) / 64, MP), 256, 0, stream>>>(hb, WgT, WALT, feat, el, er);
    k_node<<<dim3((NN + 3) / 4, MP), 256, 0, stream>>>(srcg, rowst, deg, el, er, feat, bias, zbuf);
    k_sem<<<NSEM_NB, 256, 0, stream>>>(zbuf, W1T, b1, w2, wpart);
    k_beta<<<1, 256, 0, stream>>>(wpart, beta);
    k_combine<<<(NN * DF / 8 + 255) / 256, 256, 0, stream>>>(zbuf, beta, out);
}